// Round 1
// baseline (990.370 us; speedup 1.0000x reference)
//
#include <hip/hip_runtime.h>
#include <math.h>

// Node_embedding_pendulum: per-node featurization + two small MLPs.
// Baseline: 1 thread = 1 node, fp32 VALU, weights via wave-uniform loads
// (compiler should select s_load -> SMEM pipe, v_fma with SGPR operand).

constexpr int LMAX = 8;

__global__ __launch_bounds__(256) void node_embed_kernel(
    const float* __restrict__ v,
    const float* __restrict__ force,
    const int*   __restrict__ is_moving,
    const float* __restrict__ rot_theta,   // [N,8,2,2]
    const float* __restrict__ Ws1,         // [4,192]
    const float* __restrict__ bs1,         // [192]
    const float* __restrict__ Ws2,         // [192,64]
    const float* __restrict__ bs2,         // [64]
    const float* __restrict__ Wr1,         // [32,192]
    const float* __restrict__ br1,         // [192]
    const float* __restrict__ Wr2,         // [192,64]
    const float* __restrict__ br2,         // [64]
    float* __restrict__ out,               // [N*64 scalar_out][N*64 rot_out]
    int n)
{
    const int node = blockIdx.x * blockDim.x + threadIdx.x;
    if (node >= n) return;

    // ---- load per-node inputs ----
    const float2 f2 = *reinterpret_cast<const float2*>(force + (size_t)node * 2);
    const float2 v2 = *reinterpret_cast<const float2*>(v     + (size_t)node * 2);
    const float fn = sqrtf(f2.x * f2.x + f2.y * f2.y);
    const float vn = sqrtf(v2.x * v2.x + v2.y * v2.y);
    // cos/sin of atan2(y,x) without trig:
    const float cf = f2.x / fn, sf = f2.y / fn;
    const float cv = v2.x / vn, sv = v2.y / vn;
    const int mov = is_moving[node];

    // ---- harmonics: rot_f[2k]=cos((k+1)th), rot_f[2k+1]=sin((k+1)th) ----
    float rotf[2 * LMAX], rotv[2 * LMAX];
    rotf[0] = cf; rotf[1] = sf;
    rotv[0] = cv; rotv[1] = sv;
    #pragma unroll
    for (int k = 1; k < LMAX; ++k) {
        rotf[2*k]   = rotf[2*k-2] * cf - rotf[2*k-1] * sf;
        rotf[2*k+1] = rotf[2*k-1] * cf + rotf[2*k-2] * sf;
        rotv[2*k]   = rotv[2*k-2] * cv - rotv[2*k-1] * sv;
        rotv[2*k+1] = rotv[2*k-1] * cv + rotv[2*k-2] * sv;
    }

    // ---- input rotation: x_in[j*16+2k+l] = R[k][l][0]*x0 + R[k][l][1]*x1 ----
    const float* Rbase = rot_theta + (size_t)node * 32;
    float x_in[32];
    #pragma unroll
    for (int k = 0; k < LMAX; ++k) {
        const float4 R = *reinterpret_cast<const float4*>(Rbase + k * 4);
        // R.x=R[k][0][0] R.y=R[k][0][1] R.z=R[k][1][0] R.w=R[k][1][1]
        {
            const float a = rotf[2*k], b = rotf[2*k+1];
            x_in[0*16 + 2*k + 0] = fmaf(R.x, a, R.y * b);
            x_in[0*16 + 2*k + 1] = fmaf(R.z, a, R.w * b);
        }
        {
            const float a = rotv[2*k], b = rotv[2*k+1];
            x_in[1*16 + 2*k + 0] = fmaf(R.x, a, R.y * b);
            x_in[1*16 + 2*k + 1] = fmaf(R.z, a, R.w * b);
        }
    }

    // ---- rot MLP: relu(x_in @ Wr1 + br1) @ Wr2 + br2 ----
    float acc[64];
    #pragma unroll
    for (int j = 0; j < 64; ++j) acc[j] = br2[j];

    for (int h = 0; h < 192; h += 4) {
        float hid[4];
        #pragma unroll
        for (int u = 0; u < 4; ++u) {
            float t = br1[h + u];
            #pragma unroll
            for (int i = 0; i < 32; ++i)
                t = fmaf(x_in[i], Wr1[i * 192 + h + u], t);
            hid[u] = fmaxf(t, 0.0f);
        }
        #pragma unroll
        for (int j = 0; j < 64; ++j) {
            float t = acc[j];
            t = fmaf(hid[0], Wr2[(h + 0) * 64 + j], t);
            t = fmaf(hid[1], Wr2[(h + 1) * 64 + j], t);
            t = fmaf(hid[2], Wr2[(h + 2) * 64 + j], t);
            t = fmaf(hid[3], Wr2[(h + 3) * 64 + j], t);
            acc[j] = t;
        }
    }

    // ---- output rotation in place: rot_out[j,k,l] = a*R[k,0,l] + b*R[k,1,l] ----
    #pragma unroll
    for (int k = 0; k < LMAX; ++k) {
        const float4 R = *reinterpret_cast<const float4*>(Rbase + k * 4);
        #pragma unroll
        for (int j = 0; j < 4; ++j) {
            const int p = j * 16 + 2 * k;
            const float a = acc[p], b = acc[p + 1];
            acc[p]     = fmaf(a, R.x, b * R.z);
            acc[p + 1] = fmaf(a, R.y, b * R.w);
        }
    }

    // store rot_out (second output, offset n*64)
    {
        float* orow = out + (size_t)n * 64 + (size_t)node * 64;
        #pragma unroll
        for (int j = 0; j < 16; ++j) {
            float4 w = make_float4(acc[4*j], acc[4*j+1], acc[4*j+2], acc[4*j+3]);
            *reinterpret_cast<float4*>(orow + 4 * j) = w;
        }
    }

    // ---- scalar MLP: features [fn, vn, mov==0, mov==1] ----
    const float s0 = fn, s1 = vn;
    const float s2 = (mov == 0) ? 1.0f : 0.0f;
    const float s3 = (mov == 1) ? 1.0f : 0.0f;

    #pragma unroll
    for (int j = 0; j < 64; ++j) acc[j] = bs2[j];

    for (int h = 0; h < 192; h += 4) {
        float hid[4];
        #pragma unroll
        for (int u = 0; u < 4; ++u) {
            float t = bs1[h + u];
            t = fmaf(s0, Ws1[0 * 192 + h + u], t);
            t = fmaf(s1, Ws1[1 * 192 + h + u], t);
            t = fmaf(s2, Ws1[2 * 192 + h + u], t);
            t = fmaf(s3, Ws1[3 * 192 + h + u], t);
            hid[u] = fmaxf(t, 0.0f);
        }
        #pragma unroll
        for (int j = 0; j < 64; ++j) {
            float t = acc[j];
            t = fmaf(hid[0], Ws2[(h + 0) * 64 + j], t);
            t = fmaf(hid[1], Ws2[(h + 1) * 64 + j], t);
            t = fmaf(hid[2], Ws2[(h + 2) * 64 + j], t);
            t = fmaf(hid[3], Ws2[(h + 3) * 64 + j], t);
            acc[j] = t;
        }
    }

    // store scalar_out (first output)
    {
        float* orow = out + (size_t)node * 64;
        #pragma unroll
        for (int j = 0; j < 16; ++j) {
            float4 w = make_float4(acc[4*j], acc[4*j+1], acc[4*j+2], acc[4*j+3]);
            *reinterpret_cast<float4*>(orow + 4 * j) = w;
        }
    }
}

extern "C" void kernel_launch(void* const* d_in, const int* in_sizes, int n_in,
                              void* d_out, int out_size, void* d_ws, size_t ws_size,
                              hipStream_t stream) {
    const int n = in_sizes[0] / 2;
    const dim3 block(256);
    const dim3 grid((n + 255) / 256);
    hipLaunchKernelGGL(node_embed_kernel, grid, block, 0, stream,
                       (const float*)d_in[0],   // v
                       (const float*)d_in[1],   // force
                       (const int*)  d_in[2],   // is_moving
                       (const float*)d_in[3],   // rot_theta
                       (const float*)d_in[4],   // Ws1
                       (const float*)d_in[5],   // bs1
                       (const float*)d_in[6],   // Ws2
                       (const float*)d_in[7],   // bs2
                       (const float*)d_in[8],   // Wr1
                       (const float*)d_in[9],   // br1
                       (const float*)d_in[10],  // Wr2
                       (const float*)d_in[11],  // br2
                       (float*)d_out, n);
}

// Round 2
// 374.723 us; speedup vs baseline: 2.6429x; 2.6429x over previous
//
#include <hip/hip_runtime.h>
#include <math.h>

typedef short bf16x8 __attribute__((ext_vector_type(8)));
typedef float f32x4 __attribute__((ext_vector_type(4)));
typedef unsigned short u16;
typedef unsigned int u32;

constexpr int LMAX = 8;

__device__ __forceinline__ u16 f2bf(float x) {
    u32 u = __float_as_uint(x);
    u += 0x7FFFu + ((u >> 16) & 1u);
    return (u16)(u >> 16);
}

// ---------------- weight prepack into MFMA B-fragment layout ----------------
// ws layout (u16): [0:6144) B1r, [6144:12288) B1s, [12288:24576) B2r, [24576:36864) B2s
// B-frag for 16x16x32: lane l holds B[k][col], k = 8*(l/16)+j (j=0..7), col = tile*16 + (l%16)
__global__ void prepack_kernel(const float* __restrict__ Ws1, const float* __restrict__ Ws2,
                               const float* __restrict__ Wr1, const float* __restrict__ Wr2,
                               u16* __restrict__ ws)
{
    int idx = blockIdx.x * blockDim.x + threadIdx.x;
    if (idx >= 36864) return;
    int arr, e;
    if (idx < 6144)       { arr = 0; e = idx; }
    else if (idx < 12288) { arr = 1; e = idx - 6144; }
    else if (idx < 24576) { arr = 2; e = idx - 12288; }
    else                  { arr = 3; e = idx - 24576; }
    int tile = e >> 9;          // element / 512
    int l    = (e >> 3) & 63;   // lane
    int j    = e & 7;
    int g    = l >> 4;
    float val;
    if (arr < 2) {              // GEMM1 weights: [32 x 192]
        int k   = g * 8 + j;
        int col = tile * 16 + (l & 15);
        val = (arr == 0) ? Wr1[k * 192 + col]
                         : ((k < 4) ? Ws1[k * 192 + col] : 0.0f);
    } else {                    // GEMM2 weights: [192 x 64], tile = ks*4 + nt
        int ks  = tile >> 2;
        int nt  = tile & 3;
        int k   = ks * 32 + g * 8 + j;
        int col = nt * 16 + (l & 15);
        val = (arr == 2) ? Wr2[k * 64 + col] : Ws2[k * 64 + col];
    }
    ws[idx] = f2bf(val);
}

// ---------------- main fused kernel: 1 wave = 64 nodes ----------------
__global__ __launch_bounds__(256) void node_embed_mfma(
    const float* __restrict__ v, const float* __restrict__ force,
    const int* __restrict__ is_moving, const float* __restrict__ rot_theta,
    const float* __restrict__ bs1, const float* __restrict__ bs2,
    const float* __restrict__ br1, const float* __restrict__ br2,
    const u16* __restrict__ wpack,
    float* __restrict__ out, int n)
{
    // per-wave LDS partitions (no cross-wave sharing -> no barriers)
    __shared__ u16 Xs[4][64 * 40];    // X tile: 64 rows x 40 cols (32 rot + 4 feat + 4 pad)
    __shared__ u16 Hs[4][16 * 232];   // hidden slice: 16 rows x 192 cols, stride 232

    const int lane = threadIdx.x & 63;
    const int w    = threadIdx.x >> 6;
    const int g    = lane >> 4;
    const int l15  = lane & 15;
    const int nodeBase = blockIdx.x * 256 + w * 64;

    // ---- featurization: lane = node ----
    const int node = nodeBase + lane;
    const int ldn  = min(node, n - 1);

    const float2 f2 = *reinterpret_cast<const float2*>(force + (size_t)ldn * 2);
    const float2 v2 = *reinterpret_cast<const float2*>(v     + (size_t)ldn * 2);
    const float fn = sqrtf(f2.x * f2.x + f2.y * f2.y);
    const float vn = sqrtf(v2.x * v2.x + v2.y * v2.y);
    const float cf = f2.x / fn, sf = f2.y / fn;
    const float cv = v2.x / vn, sv = v2.y / vn;
    const int mov = is_moving[ldn];

    float rotf[2 * LMAX], rotv[2 * LMAX];
    rotf[0] = cf; rotf[1] = sf;
    rotv[0] = cv; rotv[1] = sv;
    #pragma unroll
    for (int k = 1; k < LMAX; ++k) {
        rotf[2*k]   = rotf[2*k-2] * cf - rotf[2*k-1] * sf;
        rotf[2*k+1] = rotf[2*k-1] * cf + rotf[2*k-2] * sf;
        rotv[2*k]   = rotv[2*k-2] * cv - rotv[2*k-1] * sv;
        rotv[2*k+1] = rotv[2*k-1] * cv + rotv[2*k-2] * sv;
    }

    const float* Rbase = rot_theta + (size_t)ldn * 32;
    u16 xv[40];
    #pragma unroll
    for (int k = 0; k < LMAX; ++k) {
        const float4 R = *reinterpret_cast<const float4*>(Rbase + k * 4);
        {
            const float a = rotf[2*k], b = rotf[2*k+1];
            xv[2*k + 0]  = f2bf(fmaf(R.x, a, R.y * b));
            xv[2*k + 1]  = f2bf(fmaf(R.z, a, R.w * b));
        }
        {
            const float a = rotv[2*k], b = rotv[2*k+1];
            xv[16 + 2*k + 0] = f2bf(fmaf(R.x, a, R.y * b));
            xv[16 + 2*k + 1] = f2bf(fmaf(R.z, a, R.w * b));
        }
    }
    xv[32] = f2bf(fn);
    xv[33] = f2bf(vn);
    xv[34] = (mov == 0) ? 0x3F80 : 0;
    xv[35] = (mov == 1) ? 0x3F80 : 0;
    xv[36] = 0; xv[37] = 0; xv[38] = 0; xv[39] = 0;

    // stage X row (80 B) as 5 x b128 writes
    {
        u32 xu[20];
        #pragma unroll
        for (int i = 0; i < 20; ++i)
            xu[i] = (u32)xv[2*i] | ((u32)xv[2*i+1] << 16);
        uint4* xdst = reinterpret_cast<uint4*>(&Xs[w][lane * 40]);
        #pragma unroll
        for (int i = 0; i < 5; ++i)
            xdst[i] = make_uint4(xu[4*i], xu[4*i+1], xu[4*i+2], xu[4*i+3]);
    }

    // ---- hoisted bias values (per-lane col = t*16 + l15) ----
    float b1rv[12], b1sv[12], b2rv[4], b2sv[4];
    #pragma unroll
    for (int t = 0; t < 12; ++t) { b1rv[t] = br1[t*16 + l15]; b1sv[t] = bs1[t*16 + l15]; }
    #pragma unroll
    for (int t = 0; t < 4; ++t)  { b2rv[t] = br2[t*16 + l15]; b2sv[t] = bs2[t*16 + l15]; }

    const u16* B1r = wpack;
    const u16* B1s = wpack + 6144;
    const u16* B2r = wpack + 12288;
    const u16* B2s = wpack + 24576;

    for (int m = 0; m < 4; ++m) {
        const int rowA = m * 16 + l15;
        const bf16x8 a1r = *reinterpret_cast<const bf16x8*>(&Xs[w][rowA * 40 + g * 8]);
        bf16x8 a1s = {0,0,0,0,0,0,0,0};
        if (g == 0) a1s = *reinterpret_cast<const bf16x8*>(&Xs[w][rowA * 40 + 32]);

        // per-row node ids + output-rotation matrices for this m-tile
        const int kk = l15 >> 1;
        const bool even = (lane & 1) == 0;
        int   nodes_r[4];
        float4 Rr[4];
        #pragma unroll
        for (int r = 0; r < 4; ++r) {
            nodes_r[r] = nodeBase + m * 16 + g * 4 + r;
            const int ln = min(nodes_r[r], n - 1);
            Rr[r] = *reinterpret_cast<const float4*>(rot_theta + (size_t)ln * 32 + kk * 4);
        }

        // ===== rot MLP =====
        #pragma unroll
        for (int nt = 0; nt < 12; ++nt) {
            const bf16x8 b = *reinterpret_cast<const bf16x8*>(&B1r[nt * 512 + lane * 8]);
            f32x4 c = { b1rv[nt], b1rv[nt], b1rv[nt], b1rv[nt] };
            c = __builtin_amdgcn_mfma_f32_16x16x32_bf16(a1r, b, c, 0, 0, 0);
            #pragma unroll
            for (int r = 0; r < 4; ++r)
                Hs[w][(g * 4 + r) * 232 + nt * 16 + l15] = f2bf(fmaxf(c[r], 0.0f));
        }
        {
            f32x4 acc[4];
            #pragma unroll
            for (int nt = 0; nt < 4; ++nt)
                acc[nt] = f32x4{ b2rv[nt], b2rv[nt], b2rv[nt], b2rv[nt] };
            #pragma unroll
            for (int ks = 0; ks < 6; ++ks) {
                const bf16x8 a2 = *reinterpret_cast<const bf16x8*>(&Hs[w][l15 * 232 + ks * 32 + g * 8]);
                #pragma unroll
                for (int nt = 0; nt < 4; ++nt) {
                    const bf16x8 b = *reinterpret_cast<const bf16x8*>(&B2r[(ks * 4 + nt) * 512 + lane * 8]);
                    acc[nt] = __builtin_amdgcn_mfma_f32_16x16x32_bf16(a2, b, acc[nt], 0, 0, 0);
                }
            }
            // output rotation + store (col = nt*16+l15, pair lanes l^1 share (row, 2k/2k+1))
            #pragma unroll
            for (int nt = 0; nt < 4; ++nt) {
                #pragma unroll
                for (int r = 0; r < 4; ++r) {
                    const float a = acc[nt][r];
                    const float p = __shfl_xor(a, 1, 64);
                    const float res = even ? fmaf(a, Rr[r].x, p * Rr[r].z)
                                           : fmaf(p, Rr[r].y, a * Rr[r].w);
                    if (nodes_r[r] < n)
                        out[(size_t)n * 64 + (size_t)nodes_r[r] * 64 + nt * 16 + l15] = res;
                }
            }
        }

        // ===== scalar MLP =====
        #pragma unroll
        for (int nt = 0; nt < 12; ++nt) {
            const bf16x8 b = *reinterpret_cast<const bf16x8*>(&B1s[nt * 512 + lane * 8]);
            f32x4 c = { b1sv[nt], b1sv[nt], b1sv[nt], b1sv[nt] };
            c = __builtin_amdgcn_mfma_f32_16x16x32_bf16(a1s, b, c, 0, 0, 0);
            #pragma unroll
            for (int r = 0; r < 4; ++r)
                Hs[w][(g * 4 + r) * 232 + nt * 16 + l15] = f2bf(fmaxf(c[r], 0.0f));
        }
        {
            f32x4 acc[4];
            #pragma unroll
            for (int nt = 0; nt < 4; ++nt)
                acc[nt] = f32x4{ b2sv[nt], b2sv[nt], b2sv[nt], b2sv[nt] };
            #pragma unroll
            for (int ks = 0; ks < 6; ++ks) {
                const bf16x8 a2 = *reinterpret_cast<const bf16x8*>(&Hs[w][l15 * 232 + ks * 32 + g * 8]);
                #pragma unroll
                for (int nt = 0; nt < 4; ++nt) {
                    const bf16x8 b = *reinterpret_cast<const bf16x8*>(&B2s[(ks * 4 + nt) * 512 + lane * 8]);
                    acc[nt] = __builtin_amdgcn_mfma_f32_16x16x32_bf16(a2, b, acc[nt], 0, 0, 0);
                }
            }
            #pragma unroll
            for (int nt = 0; nt < 4; ++nt) {
                #pragma unroll
                for (int r = 0; r < 4; ++r) {
                    if (nodes_r[r] < n)
                        out[(size_t)nodes_r[r] * 64 + nt * 16 + l15] = acc[nt][r];
                }
            }
        }
    }
}

// ---------------- fallback (round-1 VALU kernel) if ws too small ----------------
__global__ __launch_bounds__(256) void node_embed_valu(
    const float* __restrict__ v, const float* __restrict__ force,
    const int* __restrict__ is_moving, const float* __restrict__ rot_theta,
    const float* __restrict__ Ws1, const float* __restrict__ bs1,
    const float* __restrict__ Ws2, const float* __restrict__ bs2,
    const float* __restrict__ Wr1, const float* __restrict__ br1,
    const float* __restrict__ Wr2, const float* __restrict__ br2,
    float* __restrict__ out, int n)
{
    const int node = blockIdx.x * blockDim.x + threadIdx.x;
    if (node >= n) return;
    const float2 f2 = *reinterpret_cast<const float2*>(force + (size_t)node * 2);
    const float2 v2 = *reinterpret_cast<const float2*>(v     + (size_t)node * 2);
    const float fn = sqrtf(f2.x * f2.x + f2.y * f2.y);
    const float vn = sqrtf(v2.x * v2.x + v2.y * v2.y);
    const float cf = f2.x / fn, sf = f2.y / fn;
    const float cv = v2.x / vn, sv = v2.y / vn;
    const int mov = is_moving[node];
    float rotf[16], rotv[16];
    rotf[0] = cf; rotf[1] = sf; rotv[0] = cv; rotv[1] = sv;
    #pragma unroll
    for (int k = 1; k < 8; ++k) {
        rotf[2*k]   = rotf[2*k-2] * cf - rotf[2*k-1] * sf;
        rotf[2*k+1] = rotf[2*k-1] * cf + rotf[2*k-2] * sf;
        rotv[2*k]   = rotv[2*k-2] * cv - rotv[2*k-1] * sv;
        rotv[2*k+1] = rotv[2*k-1] * cv + rotv[2*k-2] * sv;
    }
    const float* Rb = rot_theta + (size_t)node * 32;
    float x_in[32];
    #pragma unroll
    for (int k = 0; k < 8; ++k) {
        const float4 R = *reinterpret_cast<const float4*>(Rb + k * 4);
        { const float a = rotf[2*k], b = rotf[2*k+1];
          x_in[2*k] = fmaf(R.x,a,R.y*b); x_in[2*k+1] = fmaf(R.z,a,R.w*b); }
        { const float a = rotv[2*k], b = rotv[2*k+1];
          x_in[16+2*k] = fmaf(R.x,a,R.y*b); x_in[16+2*k+1] = fmaf(R.z,a,R.w*b); }
    }
    float acc[64];
    #pragma unroll
    for (int j = 0; j < 64; ++j) acc[j] = br2[j];
    for (int h = 0; h < 192; h += 4) {
        float hid[4];
        #pragma unroll
        for (int u = 0; u < 4; ++u) {
            float t = br1[h+u];
            #pragma unroll
            for (int i = 0; i < 32; ++i) t = fmaf(x_in[i], Wr1[i*192+h+u], t);
            hid[u] = fmaxf(t, 0.0f);
        }
        #pragma unroll
        for (int j = 0; j < 64; ++j) {
            float t = acc[j];
            #pragma unroll
            for (int u = 0; u < 4; ++u) t = fmaf(hid[u], Wr2[(h+u)*64+j], t);
            acc[j] = t;
        }
    }
    #pragma unroll
    for (int k = 0; k < 8; ++k) {
        const float4 R = *reinterpret_cast<const float4*>(Rb + k * 4);
        #pragma unroll
        for (int j = 0; j < 4; ++j) {
            const int p = j*16 + 2*k;
            const float a = acc[p], b = acc[p+1];
            acc[p] = fmaf(a,R.x,b*R.z); acc[p+1] = fmaf(a,R.y,b*R.w);
        }
    }
    float* orow = out + (size_t)n * 64 + (size_t)node * 64;
    #pragma unroll
    for (int j = 0; j < 16; ++j)
        *reinterpret_cast<float4*>(orow + 4*j) =
            make_float4(acc[4*j], acc[4*j+1], acc[4*j+2], acc[4*j+3]);
    const float s0 = fn, s1 = vn, s2 = (mov==0)?1.f:0.f, s3 = (mov==1)?1.f:0.f;
    #pragma unroll
    for (int j = 0; j < 64; ++j) acc[j] = bs2[j];
    for (int h = 0; h < 192; h += 4) {
        float hid[4];
        #pragma unroll
        for (int u = 0; u < 4; ++u) {
            float t = bs1[h+u];
            t = fmaf(s0, Ws1[0*192+h+u], t); t = fmaf(s1, Ws1[1*192+h+u], t);
            t = fmaf(s2, Ws1[2*192+h+u], t); t = fmaf(s3, Ws1[3*192+h+u], t);
            hid[u] = fmaxf(t, 0.0f);
        }
        #pragma unroll
        for (int j = 0; j < 64; ++j) {
            float t = acc[j];
            #pragma unroll
            for (int u = 0; u < 4; ++u) t = fmaf(hid[u], Ws2[(h+u)*64+j], t);
            acc[j] = t;
        }
    }
    orow = out + (size_t)node * 64;
    #pragma unroll
    for (int j = 0; j < 16; ++j)
        *reinterpret_cast<float4*>(orow + 4*j) =
            make_float4(acc[4*j], acc[4*j+1], acc[4*j+2], acc[4*j+3]);
}

extern "C" void kernel_launch(void* const* d_in, const int* in_sizes, int n_in,
                              void* d_out, int out_size, void* d_ws, size_t ws_size,
                              hipStream_t stream) {
    const int n = in_sizes[0] / 2;
    if (ws_size >= 36864 * sizeof(u16)) {
        hipLaunchKernelGGL(prepack_kernel, dim3(144), dim3(256), 0, stream,
                           (const float*)d_in[4], (const float*)d_in[6],
                           (const float*)d_in[8], (const float*)d_in[10],
                           (u16*)d_ws);
        hipLaunchKernelGGL(node_embed_mfma, dim3((n + 255) / 256), dim3(256), 0, stream,
                           (const float*)d_in[0], (const float*)d_in[1],
                           (const int*)d_in[2],   (const float*)d_in[3],
                           (const float*)d_in[5], (const float*)d_in[7],
                           (const float*)d_in[9], (const float*)d_in[11],
                           (const u16*)d_ws, (float*)d_out, n);
    } else {
        hipLaunchKernelGGL(node_embed_valu, dim3((n + 255) / 256), dim3(256), 0, stream,
                           (const float*)d_in[0], (const float*)d_in[1],
                           (const int*)d_in[2],   (const float*)d_in[3],
                           (const float*)d_in[4], (const float*)d_in[5],
                           (const float*)d_in[6], (const float*)d_in[7],
                           (const float*)d_in[8], (const float*)d_in[9],
                           (const float*)d_in[10],(const float*)d_in[11],
                           (float*)d_out, n);
    }
}